// Round 1
// baseline (20.195 us; speedup 1.0000x reference)
//
#include <hip/hip_runtime.h>

// Proto-distance: logits[b,q,n] = -||mean_k(support[b,n,k,:]) - query[b,q,:]||^2
// B=32, N=20, K=5, NQ=300, H=256 (fixed by setup_inputs).

#define HDIM 256
#define NN   20
#define KK   5
#define NQ   300
#define TQ   12      // query rows per block (300 % 12 == 0)
#define PAD  260     // LDS row stride in floats (breaks 256-stride bank aliasing, keeps 16B align)

__global__ __launch_bounds__(256) void proto_dist_kernel(
    const float* __restrict__ support,  // [B*NN*KK, HDIM]
    const float* __restrict__ query,    // [B*NQ, HDIM]
    float* __restrict__ out)            // [B*NQ, NN]
{
    __shared__ float proto[NN * PAD];

    const int blocksPerB = NQ / TQ;            // 25
    const int b   = blockIdx.x / blocksPerB;
    const int qb  = (blockIdx.x % blocksPerB) * TQ;
    const int tid = threadIdx.x;

    // ---- Phase 1: proto[n][h] = (1/KK) * sum_k support[b,n,k,h] ----
    {
        const int h4 = (tid & 63) * 4;   // float4 offset within a 256-float row
        const int g  = tid >> 6;         // wave group 0..3
        for (int n = g; n < NN; n += 4) {
            const float* sp = support + ((size_t)(b * NN + n) * KK) * HDIM + h4;
            float4 acc = make_float4(0.f, 0.f, 0.f, 0.f);
            #pragma unroll
            for (int k = 0; k < KK; ++k) {
                float4 v = *reinterpret_cast<const float4*>(sp + (size_t)k * HDIM);
                acc.x += v.x; acc.y += v.y; acc.z += v.z; acc.w += v.w;
            }
            const float inv = 1.0f / KK;
            float4 r = make_float4(acc.x * inv, acc.y * inv, acc.z * inv, acc.w * inv);
            *reinterpret_cast<float4*>(&proto[n * PAD + h4]) = r;
        }
    }
    __syncthreads();

    // ---- Phase 2: each thread computes one output scalar ----
    if (tid < TQ * NN) {
        const int q = qb + tid / NN;
        const int n = tid % NN;
        const float* qp = query + (size_t)(b * NQ + q) * HDIM;
        const float* pp = &proto[n * PAD];
        float acc = 0.f;
        #pragma unroll 8
        for (int h = 0; h < HDIM; h += 4) {
            float4 qv = *reinterpret_cast<const float4*>(qp + h);
            float4 pv = *reinterpret_cast<const float4*>(pp + h);
            float dx = pv.x - qv.x;
            float dy = pv.y - qv.y;
            float dz = pv.z - qv.z;
            float dw = pv.w - qv.w;
            acc += dx * dx + dy * dy + dz * dz + dw * dw;
        }
        out[(size_t)(b * NQ + q) * NN + n] = -acc;
    }
}

extern "C" void kernel_launch(void* const* d_in, const int* in_sizes, int n_in,
                              void* d_out, int out_size, void* d_ws, size_t ws_size,
                              hipStream_t stream) {
    const float* support = (const float*)d_in[0];
    const float* query   = (const float*)d_in[1];
    float* out = (float*)d_out;

    const int B = in_sizes[0] / (NN * KK * HDIM);   // 32
    dim3 grid(B * (NQ / TQ));                       // 800 blocks
    proto_dist_kernel<<<grid, dim3(256), 0, stream>>>(support, query, out);
}